// Round 2
// baseline (305.069 us; speedup 1.0000x reference)
//
#include <hip/hip_runtime.h>

#define HW_N   (512 * 512)   // 262144 mask elements
#define ROWS   512           // B*C
#define NINST  63            // ids 1..63

// -------- Threefry-2x32, 20 rounds (exact JAX semantics) --------
__device__ __forceinline__ unsigned rotl32(unsigned v, int r) {
    return (v << r) | (v >> (32 - r));
}

__device__ void threefry2x32(unsigned k0, unsigned k1,
                             unsigned x0, unsigned x1,
                             unsigned* o0, unsigned* o1) {
    const unsigned ks0 = k0, ks1 = k1;
    const unsigned ks2 = k0 ^ k1 ^ 0x1BD11BDAu;
    x0 += ks0; x1 += ks1;

    // round group 1: [13,15,26,6], inject ks1, ks2+1
    x0 += x1; x1 = rotl32(x1, 13); x1 ^= x0;
    x0 += x1; x1 = rotl32(x1, 15); x1 ^= x0;
    x0 += x1; x1 = rotl32(x1, 26); x1 ^= x0;
    x0 += x1; x1 = rotl32(x1,  6); x1 ^= x0;
    x0 += ks1; x1 += ks2 + 1u;
    // group 2: [17,29,16,24], inject ks2, ks0+2
    x0 += x1; x1 = rotl32(x1, 17); x1 ^= x0;
    x0 += x1; x1 = rotl32(x1, 29); x1 ^= x0;
    x0 += x1; x1 = rotl32(x1, 16); x1 ^= x0;
    x0 += x1; x1 = rotl32(x1, 24); x1 ^= x0;
    x0 += ks2; x1 += ks0 + 2u;
    // group 3: [13,15,26,6], inject ks0, ks1+3
    x0 += x1; x1 = rotl32(x1, 13); x1 ^= x0;
    x0 += x1; x1 = rotl32(x1, 15); x1 ^= x0;
    x0 += x1; x1 = rotl32(x1, 26); x1 ^= x0;
    x0 += x1; x1 = rotl32(x1,  6); x1 ^= x0;
    x0 += ks0; x1 += ks1 + 3u;
    // group 4: [17,29,16,24], inject ks1, ks2+4
    x0 += x1; x1 = rotl32(x1, 17); x1 ^= x0;
    x0 += x1; x1 = rotl32(x1, 29); x1 ^= x0;
    x0 += x1; x1 = rotl32(x1, 16); x1 ^= x0;
    x0 += x1; x1 = rotl32(x1, 24); x1 ^= x0;
    x0 += ks1; x1 += ks2 + 4u;
    // group 5: [13,15,26,6], inject ks2, ks0+5
    x0 += x1; x1 = rotl32(x1, 13); x1 ^= x0;
    x0 += x1; x1 = rotl32(x1, 15); x1 ^= x0;
    x0 += x1; x1 = rotl32(x1, 26); x1 ^= x0;
    x0 += x1; x1 = rotl32(x1,  6); x1 ^= x0;
    x0 += ks2; x1 += ks0 + 5u;

    *o0 = x0; *o1 = x1;
}

// ws int layout: [0..63]=cnt [64..127]=first [128..191]=second
//                [192..255]=nidx [256..319]=r(uint) [320..383]=valid
// ws float layout starts at int offset 384: l[64]

// ---- kernel 1: per-instance count + two smallest match indices ----
__global__ void icl_scan_kernel(const int* __restrict__ mask, int* __restrict__ ws) {
    const int inst = blockIdx.x + 1;
    const int tid = threadIdx.x;
    int c = 0;
    int i1 = 0x7FFFFFFF, i2 = 0x7FFFFFFF;
    for (int i = tid; i < HW_N; i += 256) {
        if (mask[i] == inst) {
            c++;
            if (i < i1) { i2 = i1; i1 = i; }
            else if (i < i2) { i2 = i; }
        }
    }
    __shared__ int scnt[256], s1[256], s2[256];
    scnt[tid] = c; s1[tid] = i1; s2[tid] = i2;
    __syncthreads();
    if (tid == 0) {
        int tot = 0, a1 = 0x7FFFFFFF, a2 = 0x7FFFFFFF;
        for (int t = 0; t < 256; t++) {
            tot += scnt[t];
            int b1 = s1[t], b2 = s2[t];
            if (b1 < a1) { int tmp = a1; a1 = b1; b1 = tmp; }
            a2 = min(min(a2, b1), b2);
        }
        ws[inst]       = tot;
        ws[64 + inst]  = (a1 == 0x7FFFFFFF) ? 0 : a1;   // first
        ws[128 + inst] = (a2 == 0x7FFFFFFF) ? 0 : a2;   // second
    }
}

// ---- kernel 2: JAX randint replication (threefry_partitionable semantics) ----
__global__ void icl_rand_kernel(int* __restrict__ ws) {
    const int inst = threadIdx.x;
    if (inst < 1 || inst > NINST) return;
    const int cnt = ws[inst];
    const int ncnt = HW_N - cnt;
    unsigned span = (unsigned)((ncnt > 1) ? ncnt : 1);  // max(ncnt,1); minval=0

    // fold_in(key(42)=(0,42), inst) = TF((0,42),(0,inst)), both words
    unsigned f0, f1;
    threefry2x32(0u, 42u, 0u, (unsigned)inst, &f0, &f1);
    // partitionable split: k_i = TF(key,(0,i)), both words
    unsigned k1a, k1b, k2a, k2b;
    threefry2x32(f0, f1, 0u, 0u, &k1a, &k1b);
    threefry2x32(f0, f1, 0u, 1u, &k2a, &k2b);
    // partitionable random_bits(k, 32, ()): counts=(0,0); result = bits1 ^ bits2
    unsigned h0, h1, l0, l1;
    threefry2x32(k1a, k1b, 0u, 0u, &h0, &h1);
    threefry2x32(k2a, k2b, 0u, 0u, &l0, &l1);
    const unsigned hi = h0 ^ h1;
    const unsigned lo = l0 ^ l1;

    unsigned mult = 65536u % span;
    mult = (mult * mult) % span;                       // uint32 wrap, like lax.mul
    unsigned r = ((hi % span) * mult + (lo % span)) % span;

    ((unsigned*)ws)[256 + inst] = r;
    ws[320 + inst] = (cnt >= 2 && ncnt > 0) ? 1 : 0;
}

// ---- kernel 3: index of the (r+1)-th negative ----
__global__ void icl_select_kernel(const int* __restrict__ mask, int* __restrict__ ws) {
    const int inst = blockIdx.x + 1;
    const unsigned r = ((const unsigned*)ws)[256 + inst];
    const int tid = threadIdx.x;
    __shared__ int chunkneg[1024];   // 1024 chunks of 256 elements
    for (int k = 0; k < 4; k++) {
        const int c = tid * 4 + k;
        const int base = c * 256;
        int neg = 0;
        for (int j = 0; j < 256; j++) neg += (mask[base + j] != inst);
        chunkneg[c] = neg;
    }
    __syncthreads();
    if (tid == 0) {
        const long long target = (long long)r + 1;
        long long cum = 0;
        int nidx = 0;
        for (int c = 0; c < 1024; c++) {
            const int neg = chunkneg[c];
            if (cum + neg >= target) {
                const int base = c * 256;
                long long need = target - cum;
                for (int j = 0; j < 256; j++) {
                    if (mask[base + j] != inst) {
                        if (--need == 0) { nidx = base + j; break; }
                    }
                }
                break;
            }
            cum += neg;
        }
        ws[192 + inst] = nidx;
    }
}

// ---- kernel 4: gather columns, hinge loss ----
__global__ void icl_dist_kernel(const float* __restrict__ feats,
                                const int* __restrict__ ws,
                                float* __restrict__ wsf) {
    const int inst = blockIdx.x + 1;
    const int valid  = ws[320 + inst];
    const int first  = ws[64 + inst];
    const int second = ws[128 + inst];
    const int nidx   = ws[192 + inst];
    const int tid = threadIdx.x;
    float sap = 0.f, san = 0.f;
    if (valid) {
        for (int row = tid; row < ROWS; row += 256) {
            const size_t off = (size_t)row * HW_N;
            const float a = feats[off + first];
            const float p = feats[off + second];
            const float n = feats[off + nidx];
            const float dp = a - p + 1e-6f;
            const float dn = a - n + 1e-6f;
            sap += dp * dp;
            san += dn * dn;
        }
    }
    __shared__ float r1[256], r2[256];
    r1[tid] = sap; r2[tid] = san;
    __syncthreads();
    for (int s = 128; s > 0; s >>= 1) {
        if (tid < s) { r1[tid] += r1[tid + s]; r2[tid] += r2[tid + s]; }
        __syncthreads();
    }
    if (tid == 0) {
        const float l = fmaxf(sqrtf(r1[0]) - sqrtf(r2[0]) + 1.0f, 0.0f);
        wsf[inst] = valid ? l : 0.0f;
    }
}

// ---- kernel 5: deterministic final reduce ----
__global__ void icl_final_kernel(const int* __restrict__ ws,
                                 const float* __restrict__ wsf,
                                 float* __restrict__ out) {
    if (threadIdx.x == 0 && blockIdx.x == 0) {
        float s = 0.f, cntv = 0.f;
        for (int i = 1; i <= NINST; i++) {
            s += wsf[i];
            cntv += (float)ws[320 + i];
        }
        out[0] = (cntv > 0.f) ? (s / fmaxf(cntv, 1.0f)) : 0.0f;
    }
}

extern "C" void kernel_launch(void* const* d_in, const int* in_sizes, int n_in,
                              void* d_out, int out_size, void* d_ws, size_t ws_size,
                              hipStream_t stream) {
    const float* feats = (const float*)d_in[0];   // (2,256,512,512) f32 -> (512, 262144)
    const int*   mask  = (const int*)d_in[1];     // (512,512) int32
    float* out = (float*)d_out;
    int*   wsi = (int*)d_ws;
    float* wsf = ((float*)d_ws) + 384;

    icl_scan_kernel  <<<NINST, 256, 0, stream>>>(mask, wsi);
    icl_rand_kernel  <<<1,     64,  0, stream>>>(wsi);
    icl_select_kernel<<<NINST, 256, 0, stream>>>(mask, wsi);
    icl_dist_kernel  <<<NINST, 256, 0, stream>>>(feats, wsi, wsf);
    icl_final_kernel <<<1,     64,  0, stream>>>(wsi, wsf, out);
}

// Round 3
// 66.958 us; speedup vs baseline: 4.5561x; 4.5561x over previous
//
#include <hip/hip_runtime.h>

#define HW_N     (512 * 512)   // 262144 mask elements
#define ROWS     512           // B*C
#define NINST    63            // ids 1..63
#define NCHUNK   256
#define CHUNK    1024          // NCHUNK*CHUNK == HW_N

// ws int layout:
//  [0..63]=cnt  [64..127]=first  [128..191]=second  [192..255]=nidx
//  [256..319]=r(uint)  [320..383]=valid
//  [384..447]=losses (float)
//  [448..447+567]=task table: inst i (1..63), task t (0..2): 3 ints {chunk,k,polarity}
//  [1024..1024+16384)=hist[chunk][64]
#define WS_TASK  448
#define WS_HIST  1024

// -------- Threefry-2x32, 20 rounds (exact JAX semantics) --------
__device__ __forceinline__ unsigned rotl32(unsigned v, int r) {
    return (v << r) | (v >> (32 - r));
}

__device__ void threefry2x32(unsigned k0, unsigned k1,
                             unsigned x0, unsigned x1,
                             unsigned* o0, unsigned* o1) {
    const unsigned ks0 = k0, ks1 = k1;
    const unsigned ks2 = k0 ^ k1 ^ 0x1BD11BDAu;
    x0 += ks0; x1 += ks1;
    x0 += x1; x1 = rotl32(x1, 13); x1 ^= x0;
    x0 += x1; x1 = rotl32(x1, 15); x1 ^= x0;
    x0 += x1; x1 = rotl32(x1, 26); x1 ^= x0;
    x0 += x1; x1 = rotl32(x1,  6); x1 ^= x0;
    x0 += ks1; x1 += ks2 + 1u;
    x0 += x1; x1 = rotl32(x1, 17); x1 ^= x0;
    x0 += x1; x1 = rotl32(x1, 29); x1 ^= x0;
    x0 += x1; x1 = rotl32(x1, 16); x1 ^= x0;
    x0 += x1; x1 = rotl32(x1, 24); x1 ^= x0;
    x0 += ks2; x1 += ks0 + 2u;
    x0 += x1; x1 = rotl32(x1, 13); x1 ^= x0;
    x0 += x1; x1 = rotl32(x1, 15); x1 ^= x0;
    x0 += x1; x1 = rotl32(x1, 26); x1 ^= x0;
    x0 += x1; x1 = rotl32(x1,  6); x1 ^= x0;
    x0 += ks0; x1 += ks1 + 3u;
    x0 += x1; x1 = rotl32(x1, 17); x1 ^= x0;
    x0 += x1; x1 = rotl32(x1, 29); x1 ^= x0;
    x0 += x1; x1 = rotl32(x1, 16); x1 ^= x0;
    x0 += x1; x1 = rotl32(x1, 24); x1 ^= x0;
    x0 += ks1; x1 += ks2 + 4u;
    x0 += x1; x1 = rotl32(x1, 13); x1 ^= x0;
    x0 += x1; x1 = rotl32(x1, 15); x1 ^= x0;
    x0 += x1; x1 = rotl32(x1, 26); x1 ^= x0;
    x0 += x1; x1 = rotl32(x1,  6); x1 ^= x0;
    x0 += ks2; x1 += ks0 + 5u;
    *o0 = x0; *o1 = x1;
}

// ---- kernel A: per-chunk histogram (mask read exactly once, full GPU) ----
__global__ void icl_hist_kernel(const int* __restrict__ mask, int* __restrict__ ws) {
    const int c = blockIdx.x;           // chunk
    const int tid = threadIdx.x;        // 256 threads, 4 elements each
    __shared__ int h[64];
    if (tid < 64) h[tid] = 0;
    __syncthreads();
    const int4 v = ((const int4*)(mask + c * CHUNK))[tid];
    if ((unsigned)v.x < 64u) atomicAdd(&h[v.x], 1);
    if ((unsigned)v.y < 64u) atomicAdd(&h[v.y], 1);
    if ((unsigned)v.z < 64u) atomicAdd(&h[v.z], 1);
    if ((unsigned)v.w < 64u) atomicAdd(&h[v.w], 1);
    __syncthreads();
    if (tid < 64) ws[WS_HIST + c * 64 + tid] = h[tid];
}

// ---- kernel B: per-inst setup — cnt, r, task table ----
__global__ void icl_setup_kernel(int* __restrict__ ws) {
    const int inst = threadIdx.x;
    if (inst < 1 || inst > NINST) return;

    // pass 1: total count
    int cnt = 0;
    for (int c = 0; c < NCHUNK; c++) cnt += ws[WS_HIST + c * 64 + inst];
    const int ncnt = HW_N - cnt;
    unsigned span = (unsigned)((ncnt > 1) ? ncnt : 1);

    // JAX randint (threefry_partitionable): fold_in(key(42), inst) -> split -> bits^bits
    unsigned f0, f1;
    threefry2x32(0u, 42u, 0u, (unsigned)inst, &f0, &f1);
    unsigned k1a, k1b, k2a, k2b;
    threefry2x32(f0, f1, 0u, 0u, &k1a, &k1b);
    threefry2x32(f0, f1, 0u, 1u, &k2a, &k2b);
    unsigned h0, h1, l0, l1;
    threefry2x32(k1a, k1b, 0u, 0u, &h0, &h1);
    threefry2x32(k2a, k2b, 0u, 0u, &l0, &l1);
    const unsigned hi = h0 ^ h1;
    const unsigned lo = l0 ^ l1;
    unsigned mult = 65536u % span;
    mult = (mult * mult) % span;
    const unsigned r = ((hi % span) * mult + (lo % span)) % span;

    // pass 2: locate first-chunk, second-chunk, negative chunk+rank
    const long long target = (long long)r + 1;
    long long negcum = 0;
    int c1 = -1, c2 = -1, hc1 = 0, cN = -1, kN = 0;
    for (int c = 0; c < NCHUNK; c++) {
        const int h = ws[WS_HIST + c * 64 + inst];
        if (h > 0) { if (c1 < 0) { c1 = c; hc1 = h; } else if (c2 < 0) c2 = c; }
        const int negs = CHUNK - h;
        if (cN < 0 && negcum + negs >= target) { cN = c; kN = (int)(target - negcum); }
        negcum += negs;
    }

    int* task = ws + WS_TASK + (inst - 1) * 9;
    // task 0: first = rank-1 match
    if (cnt >= 1) { task[0] = c1; task[1] = 1; task[2] = 1; }
    else          { task[0] = -1; ws[64 + inst] = 0; }
    // task 1: second = rank-2 match overall
    if (cnt >= 2) {
        if (hc1 >= 2) { task[3] = c1; task[4] = 2; task[5] = 1; }
        else          { task[3] = c2; task[4] = 1; task[5] = 1; }
    } else { task[3] = -1; ws[128 + inst] = 0; }
    // task 2: neg = rank-kN nonmatch in chunk cN
    if (ncnt > 0) { task[6] = cN; task[7] = kN; task[8] = 0; }
    else          { task[6] = -1; ws[192 + inst] = 0; }

    ws[inst] = cnt;
    ((unsigned*)ws)[256 + inst] = r;
    ws[320 + inst] = (cnt >= 2 && ncnt > 0) ? 1 : 0;
}

// ---- kernel C: resolve k-th (non)match within one chunk via LDS scan ----
__global__ void icl_resolve_kernel(const int* __restrict__ mask, int* __restrict__ ws) {
    const int inst = blockIdx.x + 1;
    const int t = blockIdx.y;           // task 0/1/2
    const int* task = ws + WS_TASK + (inst - 1) * 9 + t * 3;
    const int chunk = task[0];
    if (chunk < 0) return;
    const int k = task[1];
    const int pol = task[2];            // 1: ==inst, 0: !=inst
    const int tid = threadIdx.x;

    const int4 v = ((const int4*)(mask + chunk * CHUNK))[tid];
    int f0 = (v.x == inst), f1 = (v.y == inst), f2 = (v.z == inst), f3 = (v.w == inst);
    if (!pol) { f0 = !f0; f1 = !f1; f2 = !f2; f3 = !f3; }
    const int mycnt = f0 + f1 + f2 + f3;

    __shared__ int sc[256];
    sc[tid] = mycnt;
    __syncthreads();
    for (int off = 1; off < 256; off <<= 1) {
        int add = (tid >= off) ? sc[tid - off] : 0;
        __syncthreads();
        sc[tid] += add;
        __syncthreads();
    }
    const int incl = sc[tid];
    const int pre = incl - mycnt;
    if (pre < k && k <= incl) {
        int need = k - pre;
        int j = 0;
        if (f0 && --need == 0) j = 0;
        else if (f1 && --need == 0) j = 1;
        else if (f2 && --need == 0) j = 2;
        else j = 3;
        const int idx = chunk * CHUNK + tid * 4 + j;
        if (t == 0) ws[64 + inst] = idx;
        else if (t == 1) ws[128 + inst] = idx;
        else ws[192 + inst] = idx;
    }
}

// ---- kernel D: gather columns, hinge loss ----
__global__ void icl_dist_kernel(const float* __restrict__ feats,
                                const int* __restrict__ ws,
                                float* __restrict__ wsf) {
    const int inst = blockIdx.x + 1;
    const int valid  = ws[320 + inst];
    const int first  = ws[64 + inst];
    const int second = ws[128 + inst];
    const int nidx   = ws[192 + inst];
    const int tid = threadIdx.x;
    float sap = 0.f, san = 0.f;
    if (valid) {
        for (int row = tid; row < ROWS; row += 256) {
            const size_t off = (size_t)row * HW_N;
            const float a = feats[off + first];
            const float p = feats[off + second];
            const float n = feats[off + nidx];
            const float dp = a - p + 1e-6f;
            const float dn = a - n + 1e-6f;
            sap += dp * dp;
            san += dn * dn;
        }
    }
    __shared__ float r1[256], r2[256];
    r1[tid] = sap; r2[tid] = san;
    __syncthreads();
    for (int s = 128; s > 0; s >>= 1) {
        if (tid < s) { r1[tid] += r1[tid + s]; r2[tid] += r2[tid + s]; }
        __syncthreads();
    }
    if (tid == 0) {
        const float l = fmaxf(sqrtf(r1[0]) - sqrtf(r2[0]) + 1.0f, 0.0f);
        wsf[inst] = valid ? l : 0.0f;
    }
}

// ---- kernel E: deterministic final reduce ----
__global__ void icl_final_kernel(const int* __restrict__ ws,
                                 const float* __restrict__ wsf,
                                 float* __restrict__ out) {
    if (threadIdx.x == 0 && blockIdx.x == 0) {
        float s = 0.f, cntv = 0.f;
        for (int i = 1; i <= NINST; i++) {
            s += wsf[i];
            cntv += (float)ws[320 + i];
        }
        out[0] = (cntv > 0.f) ? (s / fmaxf(cntv, 1.0f)) : 0.0f;
    }
}

extern "C" void kernel_launch(void* const* d_in, const int* in_sizes, int n_in,
                              void* d_out, int out_size, void* d_ws, size_t ws_size,
                              hipStream_t stream) {
    const float* feats = (const float*)d_in[0];   // (2,256,512,512) f32 -> (512, 262144)
    const int*   mask  = (const int*)d_in[1];     // (512,512) int32
    float* out = (float*)d_out;
    int*   wsi = (int*)d_ws;
    float* wsf = ((float*)d_ws) + 384;

    icl_hist_kernel   <<<NCHUNK, 256, 0, stream>>>(mask, wsi);
    icl_setup_kernel  <<<1, 64, 0, stream>>>(wsi);
    icl_resolve_kernel<<<dim3(NINST, 3), 256, 0, stream>>>(mask, wsi);
    icl_dist_kernel   <<<NINST, 256, 0, stream>>>(feats, wsi, wsf);
    icl_final_kernel  <<<1, 64, 0, stream>>>(wsi, wsf, out);
}

// Round 4
// 19.197 us; speedup vs baseline: 15.8917x; 3.4880x over previous
//
#include <hip/hip_runtime.h>

#define HW_N     (512 * 512)   // 262144 mask elements
#define ROWS     512           // B*C
#define NINST    63            // ids 1..63
#define NCHUNK   256
#define CHUNK    1024          // NCHUNK*CHUNK == HW_N

// ws int layout:
//  [0..63]=cnt  [320..383]=valid  [384..447]=losses(float, via wsf)
//  [1024..1024+16384)=hist[chunk][64]
#define WS_HIST  1024

// -------- Threefry-2x32, 20 rounds (exact JAX partitionable semantics) ------
__device__ __forceinline__ unsigned rotl32(unsigned v, int r) {
    return (v << r) | (v >> (32 - r));
}

__device__ void threefry2x32(unsigned k0, unsigned k1,
                             unsigned x0, unsigned x1,
                             unsigned* o0, unsigned* o1) {
    const unsigned ks0 = k0, ks1 = k1;
    const unsigned ks2 = k0 ^ k1 ^ 0x1BD11BDAu;
    x0 += ks0; x1 += ks1;
    x0 += x1; x1 = rotl32(x1, 13); x1 ^= x0;
    x0 += x1; x1 = rotl32(x1, 15); x1 ^= x0;
    x0 += x1; x1 = rotl32(x1, 26); x1 ^= x0;
    x0 += x1; x1 = rotl32(x1,  6); x1 ^= x0;
    x0 += ks1; x1 += ks2 + 1u;
    x0 += x1; x1 = rotl32(x1, 17); x1 ^= x0;
    x0 += x1; x1 = rotl32(x1, 29); x1 ^= x0;
    x0 += x1; x1 = rotl32(x1, 16); x1 ^= x0;
    x0 += x1; x1 = rotl32(x1, 24); x1 ^= x0;
    x0 += ks2; x1 += ks0 + 2u;
    x0 += x1; x1 = rotl32(x1, 13); x1 ^= x0;
    x0 += x1; x1 = rotl32(x1, 15); x1 ^= x0;
    x0 += x1; x1 = rotl32(x1, 26); x1 ^= x0;
    x0 += x1; x1 = rotl32(x1,  6); x1 ^= x0;
    x0 += ks0; x1 += ks1 + 3u;
    x0 += x1; x1 = rotl32(x1, 17); x1 ^= x0;
    x0 += x1; x1 = rotl32(x1, 29); x1 ^= x0;
    x0 += x1; x1 = rotl32(x1, 16); x1 ^= x0;
    x0 += x1; x1 = rotl32(x1, 24); x1 ^= x0;
    x0 += ks1; x1 += ks2 + 4u;
    x0 += x1; x1 = rotl32(x1, 13); x1 ^= x0;
    x0 += x1; x1 = rotl32(x1, 15); x1 ^= x0;
    x0 += x1; x1 = rotl32(x1, 26); x1 ^= x0;
    x0 += x1; x1 = rotl32(x1,  6); x1 ^= x0;
    x0 += ks2; x1 += ks0 + 5u;
    *o0 = x0; *o1 = x1;
}

// inclusive block scan over 256 threads (4 waves), shfl-based
__device__ int block_scan_incl(int x, int tid, int* wsum /*LDS[4]*/) {
    const int lane = tid & 63, wid = tid >> 6;
    for (int off = 1; off < 64; off <<= 1) {
        int y = __shfl_up(x, off, 64);
        if (lane >= off) x += y;
    }
    if (lane == 63) wsum[wid] = x;
    __syncthreads();
    int add = 0;
    for (int w = 0; w < wid; w++) add += wsum[w];
    x += add;
    __syncthreads();            // wsum reusable by the next call
    return x;
}

// ---- kernel A: per-chunk histogram (mask read exactly once, full GPU) ----
__global__ void icl_hist_kernel(const int* __restrict__ mask, int* __restrict__ ws) {
    const int c = blockIdx.x;           // chunk
    const int tid = threadIdx.x;        // 256 threads, 4 elements each
    __shared__ int h[64];
    if (tid < 64) h[tid] = 0;
    __syncthreads();
    const int4 v = ((const int4*)(mask + c * CHUNK))[tid];
    if ((unsigned)v.x < 64u) atomicAdd(&h[v.x], 1);
    if ((unsigned)v.y < 64u) atomicAdd(&h[v.y], 1);
    if ((unsigned)v.z < 64u) atomicAdd(&h[v.z], 1);
    if ((unsigned)v.w < 64u) atomicAdd(&h[v.w], 1);
    __syncthreads();
    if (tid < 64) ws[WS_HIST + c * 64 + tid] = h[tid];
}

// ---- kernel B: per-inst fused setup + resolve + dist ----
__global__ void icl_inst_kernel(const int* __restrict__ mask,
                                const float* __restrict__ feats,
                                int* __restrict__ ws,
                                float* __restrict__ wsf) {
    const int inst = blockIdx.x + 1;
    const int tid = threadIdx.x;        // 256 threads; tid == chunk index

    __shared__ int wsum[4];
    __shared__ int s_cnt;
    __shared__ unsigned s_r;
    __shared__ int s_ch[3], s_k[3], s_idx[3];
    __shared__ float sred[8];

    if (tid == 0) {
        s_ch[0] = s_ch[1] = s_ch[2] = -1;
        s_k[0] = 1; s_k[1] = 0; s_k[2] = 0;
        s_idx[0] = s_idx[1] = s_idx[2] = 0;
    }

    // ---- setup: scan per-chunk hist for this inst ----
    const int h = ws[WS_HIST + tid * 64 + inst];
    const int incl = block_scan_incl(h, tid, wsum);   // contains barriers (defaults visible)
    const int excl = incl - h;
    if (tid == 255) s_cnt = incl;
    // rank-1 match chunk (k always 1)
    if (excl == 0 && incl >= 1) s_ch[0] = tid;
    // rank-2 match chunk, in-chunk rank 2-excl
    if (excl < 2 && incl >= 2) { s_ch[1] = tid; s_k[1] = 2 - excl; }
    __syncthreads();

    const int cnt = s_cnt;
    const int ncnt = HW_N - cnt;
    if (tid == 0) {
        unsigned span = (unsigned)((ncnt > 1) ? ncnt : 1);
        unsigned f0, f1, k1a, k1b, k2a, k2b, h0, h1, l0, l1;
        threefry2x32(0u, 42u, 0u, (unsigned)inst, &f0, &f1);
        threefry2x32(f0, f1, 0u, 0u, &k1a, &k1b);
        threefry2x32(f0, f1, 0u, 1u, &k2a, &k2b);
        threefry2x32(k1a, k1b, 0u, 0u, &h0, &h1);
        threefry2x32(k2a, k2b, 0u, 0u, &l0, &l1);
        const unsigned hi = h0 ^ h1, lo = l0 ^ l1;
        unsigned mult = 65536u % span;
        mult = (mult * mult) % span;
        s_r = ((hi % span) * mult + (lo % span)) % span;
    }
    __syncthreads();

    // negative: (r+1)-th nonmatch
    const long long target = (long long)s_r + 1;
    const long long negincl = (long long)(tid + 1) * CHUNK - incl;
    const long long negexcl = (long long)tid * CHUNK - excl;
    if (negexcl < target && target <= negincl) {
        s_ch[2] = tid; s_k[2] = (int)(target - negexcl);
    }
    __syncthreads();

    // ---- resolve the 3 in-chunk rank-selects ----
    for (int t = 0; t < 3; t++) {
        const int chunk = s_ch[t];          // block-uniform
        if (chunk >= 0) {
            const int k = s_k[t];
            const int4 v = ((const int4*)(mask + chunk * CHUNK))[tid];
            int f0 = (v.x == inst), f1 = (v.y == inst), f2 = (v.z == inst), f3 = (v.w == inst);
            if (t == 2) { f0 = !f0; f1 = !f1; f2 = !f2; f3 = !f3; }
            const int mycnt = f0 + f1 + f2 + f3;
            const int minc = block_scan_incl(mycnt, tid, wsum);
            const int mexc = minc - mycnt;
            if (mexc < k && k <= minc) {
                int need = k - mexc, j = 3;
                if (f0 && --need == 0) j = 0;
                else if (f1 && --need == 0) j = 1;
                else if (f2 && --need == 0) j = 2;
                s_idx[t] = chunk * CHUNK + tid * 4 + j;
            }
        }
        __syncthreads();
    }

    // ---- dist: gather 3 columns, hinge ----
    const int valid = (cnt >= 2 && ncnt > 0) ? 1 : 0;
    const int iF = s_idx[0], iS = s_idx[1], iN = s_idx[2];
    float sap = 0.f, san = 0.f;
    if (valid) {
        for (int row = tid; row < ROWS; row += 256) {
            const size_t off = (size_t)row * HW_N;
            const float a = feats[off + iF];
            const float p = feats[off + iS];
            const float n = feats[off + iN];
            const float dp = a - p + 1e-6f;
            const float dn = a - n + 1e-6f;
            sap += dp * dp;
            san += dn * dn;
        }
    }
    // wave reduce then LDS combine
    for (int off = 32; off > 0; off >>= 1) {
        sap += __shfl_down(sap, off, 64);
        san += __shfl_down(san, off, 64);
    }
    const int lane = tid & 63, wid = tid >> 6;
    if (lane == 0) { sred[wid] = sap; sred[4 + wid] = san; }
    __syncthreads();
    if (tid == 0) {
        float t1 = sred[0] + sred[1] + sred[2] + sred[3];
        float t2 = sred[4] + sred[5] + sred[6] + sred[7];
        const float l = fmaxf(sqrtf(t1) - sqrtf(t2) + 1.0f, 0.0f);
        wsf[inst] = valid ? l : 0.0f;
        ws[320 + inst] = valid;
    }
}

// ---- kernel C: deterministic final reduce ----
__global__ void icl_final_kernel(const int* __restrict__ ws,
                                 const float* __restrict__ wsf,
                                 float* __restrict__ out) {
    if (threadIdx.x == 0 && blockIdx.x == 0) {
        float s = 0.f, cntv = 0.f;
        for (int i = 1; i <= NINST; i++) {
            s += wsf[i];
            cntv += (float)ws[320 + i];
        }
        out[0] = (cntv > 0.f) ? (s / fmaxf(cntv, 1.0f)) : 0.0f;
    }
}

extern "C" void kernel_launch(void* const* d_in, const int* in_sizes, int n_in,
                              void* d_out, int out_size, void* d_ws, size_t ws_size,
                              hipStream_t stream) {
    const float* feats = (const float*)d_in[0];   // (2,256,512,512) f32 -> (512, 262144)
    const int*   mask  = (const int*)d_in[1];     // (512,512) int32
    float* out = (float*)d_out;
    int*   wsi = (int*)d_ws;
    float* wsf = ((float*)d_ws) + 384;

    icl_hist_kernel <<<NCHUNK, 256, 0, stream>>>(mask, wsi);
    icl_inst_kernel <<<NINST, 256, 0, stream>>>(mask, feats, wsi, wsf);
    icl_final_kernel<<<1, 64, 0, stream>>>(wsi, wsf, out);
}